// Round 1
// baseline (829.326 us; speedup 1.0000x reference)
//
#include <hip/hip_runtime.h>
#include <hip/hip_bf16.h>

typedef unsigned short ushort_t;
typedef __attribute__((ext_vector_type(4))) float f32x4;
typedef __attribute__((ext_vector_type(8))) short short8;

#define T_TOK 32768
#define QL    1536
#define KVL   512
#define RD    64
#define NQ    3072     // 16 heads * 192
#define ROWW  2112     // qkv_lora row: 1536+512+64
#define HS    576      // 512+64

#define BM 128
#define BN 128
#define BK 64
#define KT (QL / BK)      // 24
#define MT (T_TOK / BM)   // 256
#define NT (NQ / BN)      // 24

// -ln(10000)/32 : inv_freq_i = exp(i * NLOG) = 10000^(-i/32)
#define NLOG (-0.28782313662425572f)

static __device__ __forceinline__ short f2bf(float x) {
  __hip_bfloat16 h = __float2bfloat16(x);
  return *reinterpret_cast<short*>(&h);
}

// ---------------- Wq transpose + fp32->bf16 convert ----------------
// Wq[1536][3072] f32  ->  Wt[3072][1536] bf16
__global__ void wq_t_kernel(const float* __restrict__ Wq, ushort_t* __restrict__ Wt) {
  __shared__ float tile[32][33];
  int tx = threadIdx.x, ty = threadIdx.y;   // (32, 8)
  int n0 = blockIdx.x * 32, k0 = blockIdx.y * 32;
#pragma unroll
  for (int j = 0; j < 32; j += 8)
    tile[ty + j][tx] = Wq[(size_t)(k0 + ty + j) * NQ + n0 + tx];
  __syncthreads();
#pragma unroll
  for (int j = 0; j < 32; j += 8) {
    __hip_bfloat16 h = __float2bfloat16(tile[tx][ty + j]);
    Wt[(size_t)(n0 + ty + j) * QL + k0 + tx] = *reinterpret_cast<ushort_t*>(&h);
  }
}

// ---------------- GEMM (q_c @ Wq) + NeoX RoPE epilogue ----------------
__global__ __launch_bounds__(256) void gemm_rope_kernel(
    const float* __restrict__ qkv, const int* __restrict__ pos,
    const ushort_t* __restrict__ wt, float* __restrict__ out_q) {
  __shared__ ushort_t As[BM][72];   // padded: stride 144B = 36 words (mod 32 = 4)
  __shared__ ushort_t Bs[BN][72];
  __shared__ float pos_sh[BM];

  int bid = blockIdx.x;
  // XCD swizzle: each XCD gets 768 consecutive virtual blocks (32 m-panels)
  int vb = (bid & 7) * (MT * NT / 8) + (bid >> 3);
  int m0 = (vb / NT) * BM;
  int n0 = (vb % NT) * BN;

  int tid = threadIdx.x;
  if (tid < BM) pos_sh[tid] = (float)pos[m0 + tid];

  // staging: thread covers one row-half (32 elems) of A and of B per K-step
  int srow = tid >> 1;
  int skh  = (tid & 1) << 5;   // 0 or 32
  const float*    ag = qkv + (size_t)(m0 + srow) * ROWW + skh;  // q_c part: cols 0..1535
  const ushort_t* bg = wt  + (size_t)(n0 + srow) * QL  + skh;
  ushort_t* ad = &As[srow][skh];
  ushort_t* bd = &Bs[srow][skh];

  int lane = tid & 63, l16 = lane & 15, lq4 = lane >> 4;
  int wave = tid >> 6;
  int wm = wave >> 1, wc = wave & 1;    // 2x2 wave grid, 64x64 per wave
  const ushort_t* arow = &As[wm * 64 + l16][lq4 * 8];
  const ushort_t* brow = &Bs[wc * 64 + l16][lq4 * 8];

  f32x4 acc[4][4];
#pragma unroll
  for (int i = 0; i < 4; ++i)
#pragma unroll
    for (int j = 0; j < 4; ++j) acc[i][j] = (f32x4)0.0f;

  f32x4 ar[8];
  short8 brg[4];
#pragma unroll
  for (int i = 0; i < 8; ++i) ar[i] = *(const f32x4*)(ag + 4 * i);
#pragma unroll
  for (int i = 0; i < 4; ++i) brg[i] = *(const short8*)(bg + 8 * i);

  for (int kt = 0; kt < KT; ++kt) {
    __syncthreads();   // previous compute done reading LDS
#pragma unroll
    for (int i = 0; i < 4; ++i) {
      f32x4 lo = ar[2 * i], hi = ar[2 * i + 1];
      short8 v;
      v[0] = f2bf(lo[0]); v[1] = f2bf(lo[1]); v[2] = f2bf(lo[2]); v[3] = f2bf(lo[3]);
      v[4] = f2bf(hi[0]); v[5] = f2bf(hi[1]); v[6] = f2bf(hi[2]); v[7] = f2bf(hi[3]);
      *(short8*)(ad + 8 * i) = v;
      *(short8*)(bd + 8 * i) = brg[i];
    }
    __syncthreads();
    if (kt + 1 < KT) {   // issue next tile's global loads early (overlap with MFMA)
      const float*    ag2 = ag + (kt + 1) * BK;
      const ushort_t* bg2 = bg + (kt + 1) * BK;
#pragma unroll
      for (int i = 0; i < 8; ++i) ar[i] = *(const f32x4*)(ag2 + 4 * i);
#pragma unroll
      for (int i = 0; i < 4; ++i) brg[i] = *(const short8*)(bg2 + 8 * i);
    }
#pragma unroll
    for (int ks = 0; ks < 2; ++ks) {
      short8 af[4], bfv[4];
#pragma unroll
      for (int mi = 0; mi < 4; ++mi)
        af[mi] = *(const short8*)(arow + mi * 16 * 72 + ks * 32);
#pragma unroll
      for (int ni = 0; ni < 4; ++ni)
        bfv[ni] = *(const short8*)(brow + ni * 16 * 72 + ks * 32);
#pragma unroll
      for (int mi = 0; mi < 4; ++mi)
#pragma unroll
        for (int ni = 0; ni < 4; ++ni)
          acc[mi][ni] = __builtin_amdgcn_mfma_f32_16x16x32_bf16(
              af[mi], bfv[ni], acc[mi][ni], 0, 0, 0);
    }
  }

  // ---- epilogue: C/D layout col = lane&15, row = (lane>>4)*4 + reg ----
  int gn = n0 + wc * 64;
  bool ropew = ((gn % 192) == 128);   // rope region always 64-col aligned
  if (!ropew) {
#pragma unroll
    for (int mi = 0; mi < 4; ++mi)
#pragma unroll
      for (int r = 0; r < 4; ++r) {
        int t = m0 + wm * 64 + mi * 16 + lq4 * 4 + r;
        float* rowp = out_q + (size_t)t * NQ + gn + l16;
        rowp[0]  = acc[mi][0][r];
        rowp[16] = acc[mi][1][r];
        rowp[32] = acc[mi][2][r];
        rowp[48] = acc[mi][3][r];
      }
  } else {
    float invf0 = __expf((float)l16 * NLOG);
    float invf1 = __expf((float)(l16 + 16) * NLOG);
#pragma unroll
    for (int mi = 0; mi < 4; ++mi)
#pragma unroll
      for (int r = 0; r < 4; ++r) {
        int rl = wm * 64 + mi * 16 + lq4 * 4 + r;
        int t = m0 + rl;
        float p = pos_sh[rl];
        float s0, c0, s1, c1;
        __sincosf(p * invf0, &s0, &c0);
        __sincosf(p * invf1, &s1, &c1);
        float x1a = acc[mi][0][r], x1b = acc[mi][1][r];
        float x2a = acc[mi][2][r], x2b = acc[mi][3][r];
        float* rowp = out_q + (size_t)t * NQ + gn + l16;
        rowp[0]  = x1a * c0 - x2a * s0;
        rowp[16] = x1b * c1 - x2b * s1;
        rowp[32] = x2a * c0 + x1a * s0;
        rowp[48] = x2b * c1 + x1b * s1;
      }
  }
}

// ---------------- kv_c copy + k_pe RoPE + kv_cache scatter ----------------
__global__ void kv_kernel(const float* __restrict__ qkv, const int* __restrict__ pos,
                          const int* __restrict__ slots,
                          float* __restrict__ out_kvc, float* __restrict__ out_kpe,
                          float* __restrict__ out_cache) {
  int tok = blockIdx.x * 4 + (threadIdx.x >> 6);
  int lane = threadIdx.x & 63;
  const float* src = qkv + (size_t)tok * ROWW + QL;   // kv_c (512) then k_pe (64)
  float* dkv = out_kvc + (size_t)tok * KVL;
  int slot = slots[tok];
  float* dc = out_cache + (size_t)slot * HS;
#pragma unroll
  for (int i = 0; i < 2; ++i) {
    f32x4 v = *(const f32x4*)(src + (size_t)(lane + 64 * i) * 4);
    *(f32x4*)(dkv + (size_t)(lane + 64 * i) * 4) = v;
    *(f32x4*)(dc + (size_t)(lane + 64 * i) * 4) = v;
  }
  if (lane < 32) {
    float x1 = src[KVL + lane], x2 = src[KVL + 32 + lane];
    float p = (float)pos[tok];
    float invf = __expf((float)lane * NLOG);
    float s, c;
    __sincosf(p * invf, &s, &c);
    float r1 = x1 * c - x2 * s;
    float r2 = x2 * c + x1 * s;
    out_kpe[(size_t)tok * RD + lane] = r1;
    out_kpe[(size_t)tok * RD + 32 + lane] = r2;
    dc[KVL + lane] = r1;
    dc[KVL + 32 + lane] = r2;
  }
}

extern "C" void kernel_launch(void* const* d_in, const int* in_sizes, int n_in,
                              void* d_out, int out_size, void* d_ws, size_t ws_size,
                              hipStream_t stream) {
  const float* qkv      = (const float*)d_in[0];
  const int*   positions= (const int*)d_in[1];
  const float* Wq       = (const float*)d_in[2];
  // d_in[3] = kv_cache input (all rows overwritten: slot_mapping is a permutation)
  const int*   slots    = (const int*)d_in[4];

  float* out_q     = (float*)d_out;
  float* out_kvc   = out_q   + (size_t)T_TOK * NQ;
  float* out_kpe   = out_kvc + (size_t)T_TOK * KVL;
  float* out_cache = out_kpe + (size_t)T_TOK * RD;

  // scratch for Wq^T bf16 (9.4 MB): prefer ws; else alias into kv_cache output
  // region, which kv_kernel fully rewrites afterwards (stream-ordered).
  size_t wt_bytes = (size_t)NQ * QL * sizeof(ushort_t);
  ushort_t* wt = (ws_size >= wt_bytes) ? (ushort_t*)d_ws : (ushort_t*)out_cache;

  wq_t_kernel<<<dim3(NQ / 32, QL / 32), dim3(32, 8), 0, stream>>>(Wq, wt);
  gemm_rope_kernel<<<dim3(MT * NT), dim3(256), 0, stream>>>(qkv, positions, wt, out_q);
  kv_kernel<<<dim3(T_TOK / 4), dim3(256), 0, stream>>>(qkv, positions, slots,
                                                       out_kvc, out_kpe, out_cache);
}

// Round 2
// 624.732 us; speedup vs baseline: 1.3275x; 1.3275x over previous
//
#include <hip/hip_runtime.h>
#include <hip/hip_bf16.h>
#include <stdint.h>

typedef unsigned short ushort_t;
typedef __attribute__((ext_vector_type(4))) float f32x4;
typedef __attribute__((ext_vector_type(8))) short short8;

#define T_TOK 32768
#define QL    1536
#define KVL   512
#define RD    64
#define NQ    3072     // 16 heads * 192
#define ROWW  2112     // qkv_lora row: 1536+512+64
#define HS    576      // 512+64

#define BM 128
#define BN 128
#define BK 64
#define KT (QL / BK)      // 24
#define MT (T_TOK / BM)   // 256
#define NT (NQ / BN)      // 24

// -ln(10000)/32 : inv_freq_i = exp(i * NLOG) = 10000^(-i/32)
#define NLOG (-0.28782313662425572f)

static __device__ __forceinline__ short f2bf(float x) {
  __hip_bfloat16 h = __float2bfloat16(x);
  return *reinterpret_cast<short*>(&h);
}

// async global->LDS, 16B per lane; LDS dest is wave-uniform base + lane*16
#define GLOAD16(gp, lp)                                        \
  __builtin_amdgcn_global_load_lds(                            \
      (const __attribute__((address_space(1))) void*)(gp),     \
      (__attribute__((address_space(3))) void*)(lp), 16, 0, 0)

// ---------------- q_c fp32 (strided) -> Abf bf16 [32768][1536] ----------------
__global__ __launch_bounds__(256) void aconv_kernel(const float* __restrict__ qkv,
                                                    ushort_t* __restrict__ Abf) {
  int g = blockIdx.x * 256 + threadIdx.x;   // one 8-elem group per thread
  int row = g / 192;                        // 192 groups per row
  int col = (g - row * 192) * 8;
  const float* s = qkv + (size_t)row * ROWW + col;
  f32x4 a = *(const f32x4*)s;
  f32x4 b = *(const f32x4*)(s + 4);
  short8 v;
  v[0] = f2bf(a[0]); v[1] = f2bf(a[1]); v[2] = f2bf(a[2]); v[3] = f2bf(a[3]);
  v[4] = f2bf(b[0]); v[5] = f2bf(b[1]); v[6] = f2bf(b[2]); v[7] = f2bf(b[3]);
  *(short8*)(Abf + (size_t)row * QL + col) = v;
}

// ---------------- Wq transpose + fp32->bf16: Wq[1536][3072] -> Wt[3072][1536] ----
__global__ void wq_t_kernel(const float* __restrict__ Wq, ushort_t* __restrict__ Wt) {
  __shared__ float tile[32][33];
  int tx = threadIdx.x, ty = threadIdx.y;   // (32, 8)
  int n0 = blockIdx.x * 32, k0 = blockIdx.y * 32;
#pragma unroll
  for (int j = 0; j < 32; j += 8)
    tile[ty + j][tx] = Wq[(size_t)(k0 + ty + j) * NQ + n0 + tx];
  __syncthreads();
#pragma unroll
  for (int j = 0; j < 32; j += 8)
    Wt[(size_t)(n0 + ty + j) * QL + k0 + tx] = f2bf(tile[tx][ty + j]);
}

// ---------------- bf16 GEMM (Abf @ Wt^T) + NeoX RoPE epilogue ----------------
// m97 structure: 128x128 tile, BK=64, global_load_lds width-16, linear LDS,
// 2 barriers per K-step, 4 waves x (4x4 of 16x16x32 MFMA).
__global__ __launch_bounds__(256) void gemm_rope_kernel(
    const ushort_t* __restrict__ Abf, const int* __restrict__ pos,
    const ushort_t* __restrict__ wt, float* __restrict__ out_q) {
  __shared__ ushort_t As[BM * BK];   // 16 KB, linear (global_load_lds needs it)
  __shared__ ushort_t Bs[BN * BK];   // 16 KB
  __shared__ float pos_sh[BM];

  int bid = blockIdx.x;
  // XCD swizzle (6144 % 8 == 0 -> bijective): 768 consecutive vb per XCD
  int vb = (bid & 7) * (MT * NT / 8) + (bid >> 3);
  int m0 = (vb / NT) * BM;
  int n0 = (vb % NT) * BN;

  int tid = threadIdx.x;
  if (tid < BM) pos_sh[tid] = (float)pos[m0 + tid];

  int wv = tid >> 6, ln = tid & 63;
  int l16 = ln & 15, lq4 = ln >> 4;
  int wm = wv >> 1, wc = wv & 1;        // 2x2 wave grid, 64x64 per wave

  // staging: wave wv, instr i covers LDS bytes [(wv*4+i)*1024, +1024)
  // = rows (wv*4+i)*8 + ln/8, elem col (ln%8)*8 of the [128][64] tile
  int srow = ln >> 3;
  int scol = (ln & 7) * 8;
  const ushort_t* agbase = Abf + (size_t)m0 * QL;
  const ushort_t* bgbase = wt + (size_t)n0 * QL;

  const ushort_t* arow = As + (wm * 64 + l16) * BK + lq4 * 8;
  const ushort_t* brow = Bs + (wc * 64 + l16) * BK + lq4 * 8;

  f32x4 acc[4][4];
#pragma unroll
  for (int i = 0; i < 4; ++i)
#pragma unroll
    for (int j = 0; j < 4; ++j) acc[i][j] = (f32x4)0.0f;

  for (int kt = 0; kt < KT; ++kt) {
    __syncthreads();                       // prev compute done reading LDS
    int kc = kt * BK;
#pragma unroll
    for (int i = 0; i < 4; ++i) {
      int r = (wv * 4 + i) * 8 + srow;
      GLOAD16(agbase + (size_t)r * QL + kc + scol, As + (wv * 4 + i) * 512);
      GLOAD16(bgbase + (size_t)r * QL + kc + scol, Bs + (wv * 4 + i) * 512);
    }
    __syncthreads();                       // compiler drains vmcnt before barrier
#pragma unroll
    for (int ks = 0; ks < 2; ++ks) {
      short8 af[4], bfv[4];
#pragma unroll
      for (int mi = 0; mi < 4; ++mi)
        af[mi] = *(const short8*)(arow + mi * 16 * BK + ks * 32);
#pragma unroll
      for (int ni = 0; ni < 4; ++ni)
        bfv[ni] = *(const short8*)(brow + ni * 16 * BK + ks * 32);
#pragma unroll
      for (int mi = 0; mi < 4; ++mi)
#pragma unroll
        for (int ni = 0; ni < 4; ++ni)
          acc[mi][ni] = __builtin_amdgcn_mfma_f32_16x16x32_bf16(
              af[mi], bfv[ni], acc[mi][ni], 0, 0, 0);
    }
  }

  // ---- epilogue: C/D layout col = lane&15, row = (lane>>4)*4 + reg ----
  int gn = n0 + wc * 64;
  bool ropew = ((gn % 192) == 128);   // rope region is always 64-col aligned
  if (!ropew) {
#pragma unroll
    for (int mi = 0; mi < 4; ++mi)
#pragma unroll
      for (int r = 0; r < 4; ++r) {
        int t = m0 + wm * 64 + mi * 16 + lq4 * 4 + r;
        float* rowp = out_q + (size_t)t * NQ + gn + l16;
        rowp[0]  = acc[mi][0][r];
        rowp[16] = acc[mi][1][r];
        rowp[32] = acc[mi][2][r];
        rowp[48] = acc[mi][3][r];
      }
  } else {
    float invf0 = __expf((float)l16 * NLOG);
    float invf1 = __expf((float)(l16 + 16) * NLOG);
#pragma unroll
    for (int mi = 0; mi < 4; ++mi)
#pragma unroll
      for (int r = 0; r < 4; ++r) {
        int rl = wm * 64 + mi * 16 + lq4 * 4 + r;
        int t = m0 + rl;
        float p = pos_sh[rl];
        float s0, c0, s1, c1;
        __sincosf(p * invf0, &s0, &c0);
        __sincosf(p * invf1, &s1, &c1);
        float x1a = acc[mi][0][r], x1b = acc[mi][1][r];
        float x2a = acc[mi][2][r], x2b = acc[mi][3][r];
        float* rowp = out_q + (size_t)t * NQ + gn + l16;
        rowp[0]  = x1a * c0 - x2a * s0;
        rowp[16] = x1b * c1 - x2b * s1;
        rowp[32] = x2a * c0 + x1a * s0;
        rowp[48] = x2b * c1 + x1b * s1;
      }
  }
}

// ---------------- kv_c copy + k_pe RoPE + kv_cache scatter ----------------
__global__ void kv_kernel(const float* __restrict__ qkv, const int* __restrict__ pos,
                          const int* __restrict__ slots,
                          float* __restrict__ out_kvc, float* __restrict__ out_kpe,
                          float* __restrict__ out_cache) {
  int tok = blockIdx.x * 4 + (threadIdx.x >> 6);
  int lane = threadIdx.x & 63;
  const float* src = qkv + (size_t)tok * ROWW + QL;   // kv_c (512) then k_pe (64)
  float* dkv = out_kvc + (size_t)tok * KVL;
  int slot = slots[tok];
  float* dc = out_cache + (size_t)slot * HS;
#pragma unroll
  for (int i = 0; i < 2; ++i) {
    f32x4 v = *(const f32x4*)(src + (size_t)(lane + 64 * i) * 4);
    *(f32x4*)(dkv + (size_t)(lane + 64 * i) * 4) = v;
    *(f32x4*)(dc + (size_t)(lane + 64 * i) * 4) = v;
  }
  if (lane < 32) {
    float x1 = src[KVL + lane], x2 = src[KVL + 32 + lane];
    float p = (float)pos[tok];
    float invf = __expf((float)lane * NLOG);
    float s, c;
    __sincosf(p * invf, &s, &c);
    float r1 = x1 * c - x2 * s;
    float r2 = x2 * c + x1 * s;
    out_kpe[(size_t)tok * RD + lane] = r1;
    out_kpe[(size_t)tok * RD + 32 + lane] = r2;
    dc[KVL + lane] = r1;
    dc[KVL + 32 + lane] = r2;
  }
}

extern "C" void kernel_launch(void* const* d_in, const int* in_sizes, int n_in,
                              void* d_out, int out_size, void* d_ws, size_t ws_size,
                              hipStream_t stream) {
  const float* qkv       = (const float*)d_in[0];
  const int*   positions = (const int*)d_in[1];
  const float* Wq        = (const float*)d_in[2];
  // d_in[3] = kv_cache input (fully overwritten: slot_mapping is a permutation)
  const int*   slots     = (const int*)d_in[4];

  float* out_q     = (float*)d_out;
  float* out_kvc   = out_q   + (size_t)T_TOK * NQ;
  float* out_kpe   = out_kvc + (size_t)T_TOK * KVL;
  float* out_cache = out_kpe + (size_t)T_TOK * RD;

  // scratch: Abf bf16 (100.7 MB) + Wt bf16 (9.4 MB).
  // Prefer d_ws; else alias into out_kvc.. region (147.5 MB contiguous),
  // which kv_kernel fully rewrites afterwards (stream-ordered, deterministic).
  size_t abf_bytes = (size_t)T_TOK * QL * sizeof(ushort_t);   // 100,663,296
  size_t wt_bytes  = (size_t)NQ * QL * sizeof(ushort_t);      //   9,437,184
  char* scratch = (ws_size >= abf_bytes + wt_bytes) ? (char*)d_ws : (char*)out_kvc;
  ushort_t* Abf = (ushort_t*)scratch;
  ushort_t* Wt  = (ushort_t*)(scratch + abf_bytes);

  aconv_kernel<<<dim3(T_TOK * 192 / 256), dim3(256), 0, stream>>>(qkv, Abf);
  wq_t_kernel<<<dim3(NQ / 32, QL / 32), dim3(32, 8), 0, stream>>>(Wq, Wt);
  gemm_rope_kernel<<<dim3(MT * NT), dim3(256), 0, stream>>>(Abf, positions, Wt, out_q);
  kv_kernel<<<dim3(T_TOK / 4), dim3(256), 0, stream>>>(qkv, positions, slots,
                                                       out_kvc, out_kpe, out_cache);
}

// Round 3
// 497.972 us; speedup vs baseline: 1.6654x; 1.2546x over previous
//
#include <hip/hip_runtime.h>
#include <hip/hip_bf16.h>
#include <stdint.h>

typedef unsigned short ushort_t;
typedef __attribute__((ext_vector_type(4))) float f32x4;
typedef __attribute__((ext_vector_type(8))) short short8;

#define T_TOK 32768
#define QL    1536
#define KVL   512
#define RD    64
#define NQ    3072     // 16 heads * 192
#define ROWW  2112     // qkv_lora row: 1536+512+64
#define HS    576      // 512+64

// 8-phase 256^2 GEMM geometry
#define BM 256
#define BN 256
#define BK 64
#define KT (QL / BK)       // 24 K-tiles
#define MT (T_TOK / BM)    // 128
#define NT (NQ / BN)       // 12

// -ln(10000)/32 : inv_freq_i = exp(i * NLOG) = 10000^(-i/32)
#define NLOG (-0.28782313662425572f)

static __device__ __forceinline__ short f2bf(float x) {
  __hip_bfloat16 h = __float2bfloat16(x);
  return *reinterpret_cast<short*>(&h);
}

// async global->LDS, 16B per lane; LDS dest = wave-uniform base + lane*16
#define GLOAD16(gp, lp)                                        \
  __builtin_amdgcn_global_load_lds(                            \
      (const __attribute__((address_space(1))) void*)(gp),     \
      (__attribute__((address_space(3))) void*)(lp), 16, 0, 0)

// ---------------- q_c fp32 (strided) -> Abf bf16 [32768][1536] ----------------
__global__ __launch_bounds__(256) void aconv_kernel(const float* __restrict__ qkv,
                                                    ushort_t* __restrict__ Abf) {
  int g = blockIdx.x * 256 + threadIdx.x;   // one 8-elem group per thread
  int row = g / 192;                        // 192 groups per row
  int col = (g - row * 192) * 8;
  const float* s = qkv + (size_t)row * ROWW + col;
  f32x4 a = *(const f32x4*)s;
  f32x4 b = *(const f32x4*)(s + 4);
  short8 v;
  v[0] = f2bf(a[0]); v[1] = f2bf(a[1]); v[2] = f2bf(a[2]); v[3] = f2bf(a[3]);
  v[4] = f2bf(b[0]); v[5] = f2bf(b[1]); v[6] = f2bf(b[2]); v[7] = f2bf(b[3]);
  *(short8*)(Abf + (size_t)row * QL + col) = v;
}

// ---------------- Wq transpose + fp32->bf16: Wq[1536][3072] -> Wt[3072][1536] ----
__global__ void wq_t_kernel(const float* __restrict__ Wq, ushort_t* __restrict__ Wt) {
  __shared__ float tile[32][33];
  int tx = threadIdx.x, ty = threadIdx.y;   // (32, 8)
  int n0 = blockIdx.x * 32, k0 = blockIdx.y * 32;
#pragma unroll
  for (int j = 0; j < 32; j += 8)
    tile[ty + j][tx] = Wq[(size_t)(k0 + ty + j) * NQ + n0 + tx];
  __syncthreads();
#pragma unroll
  for (int j = 0; j < 32; j += 8)
    Wt[(size_t)(n0 + ty + j) * QL + k0 + tx] = f2bf(tile[tx][ty + j]);
}

// ---------------- bf16 GEMM (Abf @ Wt^T), 256^2 8-phase + RoPE epilogue --------
// T2: LDS chunk-swizzle (16B chunk c of row r holds global chunk c^(r&7));
//     linear gload_lds dest + inverse-swizzled global src + swizzled ds_read.
// T3/T4: 4 compute phases per K-tile, counted vmcnt(8), raw s_barrier.
// T5: setprio(1) around each 16-MFMA cluster.
__global__ __launch_bounds__(512, 2) void gemm_rope_kernel(
    const ushort_t* __restrict__ Abf, const int* __restrict__ pos,
    const ushort_t* __restrict__ wt, float* __restrict__ out_q) {
  __shared__ ushort_t lds[2][2][BM * BK];   // [dbuf][A/B][256*64] = 128 KiB

  int bid = blockIdx.x;
  // XCD swizzle (1536 % 8 == 0 -> bijective): 192 consecutive vb per XCD
  int vb = (bid & 7) * (MT * NT / 8) + (bid >> 3);
  int m0 = (vb / NT) * BM;
  int n0 = (vb % NT) * BN;

  int tid = threadIdx.x;
  int wv = tid >> 6, ln = tid & 63;
  int l16 = ln & 15, lq4 = ln >> 4;
  int wm = wv >> 2, wn = wv & 3;          // 2x4 wave grid; wave owns 128x64 of C

  // ---- staging addresses (per-lane inverse-swizzled global source) ----
  int lrow = ln >> 3;                      // 0..7 row within 8-row slab
  int csrc = ((ln & 7) ^ lrow) * 8;        // inverse-swizzled 16B chunk (elems)
  const ushort_t* aG = Abf + (size_t)(m0 + wv * 8 + lrow) * QL + csrc;
  const ushort_t* bG = wt  + (size_t)(n0 + wv * 8 + lrow) * QL + csrc;

  // ---- fragment read addressing (swizzled) ----
  // row&7 == l16&7 for all fragment rows; chunk(ks) = (lq4 + 4*ks) ^ (l16&7)
  int sw = lq4 ^ (l16 & 7);                // chunk for ks=0; ks=1 -> sw^4

  f32x4 acc[8][4];
#pragma unroll
  for (int i = 0; i < 8; ++i)
#pragma unroll
    for (int j = 0; j < 4; ++j) acc[i][j] = (f32x4)0.0f;

  // ---- prologue: stage tiles 0 and 1 (8 gloads per wave per tile) ----
#pragma unroll
  for (int j = 0; j < 4; ++j) {
    GLOAD16(aG + (size_t)j * 64 * QL + 0 * BK, &lds[0][0][(j * 64 + wv * 8) * BK]);
    GLOAD16(bG + (size_t)j * 64 * QL + 0 * BK, &lds[0][1][(j * 64 + wv * 8) * BK]);
  }
#pragma unroll
  for (int j = 0; j < 4; ++j) {
    GLOAD16(aG + (size_t)j * 64 * QL + 1 * BK, &lds[1][0][(j * 64 + wv * 8) * BK]);
    GLOAD16(bG + (size_t)j * 64 * QL + 1 * BK, &lds[1][1][(j * 64 + wv * 8) * BK]);
  }

  for (int t = 0; t < KT; ++t) {
    // tile t's 8 loads are the oldest outstanding; leave t+1's 8 in flight
    if (t + 1 < KT) { asm volatile("s_waitcnt vmcnt(8)" ::: "memory"); }
    else            { asm volatile("s_waitcnt vmcnt(0)" ::: "memory"); }
    __builtin_amdgcn_s_barrier();          // all waves' tile-t loads landed
    __builtin_amdgcn_sched_barrier(0);

    const ushort_t* Ab = &lds[t & 1][0][0];
    const ushort_t* Bb = &lds[t & 1][1][0];

#pragma unroll
    for (int p = 0; p < 4; ++p) {
      const int ks = p & 1, hf = p >> 1;
      const int co = (sw ^ (ks * 4)) * 8;  // swizzled chunk offset (elems)
      short8 af[4], bfv[4];
#pragma unroll
      for (int q = 0; q < 4; ++q) {
        int mi = hf * 4 + q;
        af[q]  = *(const short8*)(Ab + (wm * 128 + mi * 16 + l16) * BK + co);
        bfv[q] = *(const short8*)(Bb + (wn * 64  + q  * 16 + l16) * BK + co);
      }
      __builtin_amdgcn_s_barrier();
      asm volatile("s_waitcnt lgkmcnt(0)" ::: "memory");
      __builtin_amdgcn_sched_barrier(0);
      __builtin_amdgcn_s_setprio(1);
#pragma unroll
      for (int q = 0; q < 4; ++q)
#pragma unroll
        for (int ni = 0; ni < 4; ++ni)
          acc[hf * 4 + q][ni] = __builtin_amdgcn_mfma_f32_16x16x32_bf16(
              af[q], bfv[ni], acc[hf * 4 + q][ni], 0, 0, 0);
      __builtin_amdgcn_s_setprio(0);
      __builtin_amdgcn_s_barrier();        // all waves done reading this phase
    }

    // buf[t&1] fully consumed by ALL waves (every wave passed lgkmcnt(0)
    // before the last barrier) -> safe to overwrite with tile t+2
    if (t + 2 < KT) {
      int kc = (t + 2) * BK;
#pragma unroll
      for (int j = 0; j < 4; ++j) {
        GLOAD16(aG + (size_t)j * 64 * QL + kc, &lds[t & 1][0][(j * 64 + wv * 8) * BK]);
        GLOAD16(bG + (size_t)j * 64 * QL + kc, &lds[t & 1][1][(j * 64 + wv * 8) * BK]);
      }
    }
  }

  // ---- epilogue: C/D layout col = lane&15, row = (lane>>4)*4 + reg ----
  int gn = n0 + wn * 64;
  bool ropew = ((gn % 192) == 128);        // rope region is 64-wide, 64-aligned
  if (!ropew) {
#pragma unroll
    for (int mi = 0; mi < 8; ++mi)
#pragma unroll
      for (int r = 0; r < 4; ++r) {
        int t = m0 + wm * 128 + mi * 16 + lq4 * 4 + r;
        float* rowp = out_q + (size_t)t * NQ + gn + l16;
        rowp[0]  = acc[mi][0][r];
        rowp[16] = acc[mi][1][r];
        rowp[32] = acc[mi][2][r];
        rowp[48] = acc[mi][3][r];
      }
  } else {
    float invf0 = __expf((float)l16 * NLOG);
    float invf1 = __expf((float)(l16 + 16) * NLOG);
#pragma unroll
    for (int mi = 0; mi < 8; ++mi)
#pragma unroll
      for (int r = 0; r < 4; ++r) {
        int t = m0 + wm * 128 + mi * 16 + lq4 * 4 + r;
        float p = (float)pos[t];
        float s0, c0, s1, c1;
        __sincosf(p * invf0, &s0, &c0);
        __sincosf(p * invf1, &s1, &c1);
        float x1a = acc[mi][0][r], x1b = acc[mi][1][r];
        float x2a = acc[mi][2][r], x2b = acc[mi][3][r];
        float* rowp = out_q + (size_t)t * NQ + gn + l16;
        rowp[0]  = x1a * c0 - x2a * s0;
        rowp[16] = x1b * c1 - x2b * s1;
        rowp[32] = x2a * c0 + x1a * s0;
        rowp[48] = x2b * c1 + x1b * s1;
      }
  }
}

// ---------------- kv_c copy + k_pe RoPE + kv_cache scatter ----------------
__global__ void kv_kernel(const float* __restrict__ qkv, const int* __restrict__ pos,
                          const int* __restrict__ slots,
                          float* __restrict__ out_kvc, float* __restrict__ out_kpe,
                          float* __restrict__ out_cache) {
  int tok = blockIdx.x * 4 + (threadIdx.x >> 6);
  int lane = threadIdx.x & 63;
  const float* src = qkv + (size_t)tok * ROWW + QL;   // kv_c (512) then k_pe (64)
  float* dkv = out_kvc + (size_t)tok * KVL;
  int slot = slots[tok];
  float* dc = out_cache + (size_t)slot * HS;
#pragma unroll
  for (int i = 0; i < 2; ++i) {
    f32x4 v = *(const f32x4*)(src + (size_t)(lane + 64 * i) * 4);
    *(f32x4*)(dkv + (size_t)(lane + 64 * i) * 4) = v;
    *(f32x4*)(dc + (size_t)(lane + 64 * i) * 4) = v;
  }
  if (lane < 32) {
    float x1 = src[KVL + lane], x2 = src[KVL + 32 + lane];
    float p = (float)pos[tok];
    float invf = __expf((float)lane * NLOG);
    float s, c;
    __sincosf(p * invf, &s, &c);
    float r1 = x1 * c - x2 * s;
    float r2 = x2 * c + x1 * s;
    out_kpe[(size_t)tok * RD + lane] = r1;
    out_kpe[(size_t)tok * RD + 32 + lane] = r2;
    dc[KVL + lane] = r1;
    dc[KVL + 32 + lane] = r2;
  }
}

extern "C" void kernel_launch(void* const* d_in, const int* in_sizes, int n_in,
                              void* d_out, int out_size, void* d_ws, size_t ws_size,
                              hipStream_t stream) {
  const float* qkv       = (const float*)d_in[0];
  const int*   positions = (const int*)d_in[1];
  const float* Wq        = (const float*)d_in[2];
  // d_in[3] = kv_cache input (fully overwritten: slot_mapping is a permutation)
  const int*   slots     = (const int*)d_in[4];

  float* out_q     = (float*)d_out;
  float* out_kvc   = out_q   + (size_t)T_TOK * NQ;
  float* out_kpe   = out_kvc + (size_t)T_TOK * KVL;
  float* out_cache = out_kpe + (size_t)T_TOK * RD;

  // scratch: Abf bf16 (100.7 MB) + Wt bf16 (9.4 MB).
  // Prefer d_ws; else alias into out_kvc.. region (147.5 MB contiguous),
  // which kv_kernel fully rewrites afterwards (stream-ordered, deterministic).
  size_t abf_bytes = (size_t)T_TOK * QL * sizeof(ushort_t);   // 100,663,296
  size_t wt_bytes  = (size_t)NQ * QL * sizeof(ushort_t);      //   9,437,184
  char* scratch = (ws_size >= abf_bytes + wt_bytes) ? (char*)d_ws : (char*)out_kvc;
  ushort_t* Abf = (ushort_t*)scratch;
  ushort_t* Wt  = (ushort_t*)(scratch + abf_bytes);

  aconv_kernel<<<dim3(T_TOK * 192 / 256), dim3(256), 0, stream>>>(qkv, Abf);
  wq_t_kernel<<<dim3(NQ / 32, QL / 32), dim3(32, 8), 0, stream>>>(Wq, Wt);
  gemm_rope_kernel<<<dim3(MT * NT), dim3(512), 0, stream>>>(Abf, positions, Wt, out_q);
  kv_kernel<<<dim3(T_TOK / 4), dim3(256), 0, stream>>>(qkv, positions, slots,
                                                       out_kvc, out_kpe, out_cache);
}

// Round 4
// 440.422 us; speedup vs baseline: 1.8830x; 1.1307x over previous
//
#include <hip/hip_runtime.h>
#include <hip/hip_bf16.h>
#include <stdint.h>

typedef unsigned short ushort_t;
typedef __attribute__((ext_vector_type(4))) float f32x4;
typedef __attribute__((ext_vector_type(8))) short short8;

#define T_TOK 32768
#define QL    1536
#define KVL   512
#define RD    64
#define NQ    3072     // 16 heads * 192
#define ROWW  2112     // qkv_lora row: 1536+512+64
#define HS    576      // 512+64

// 256^2 fine-grained 4-phase GEMM geometry
#define BM 256
#define BN 256
#define BK 64
#define KT (QL / BK)       // 24 K-tiles
#define MT (T_TOK / BM)    // 128
#define NT (NQ / BN)       // 12

// -ln(10000)/32 : inv_freq_i = exp(i * NLOG) = 10000^(-i/32)
#define NLOG (-0.28782313662425572f)

static __device__ __forceinline__ short f2bf(float x) {
  __hip_bfloat16 h = __float2bfloat16(x);
  return *reinterpret_cast<short*>(&h);
}

// async global->LDS, 16B per lane; LDS dest = wave-uniform base + lane*16
#define GLOAD16(gp, lp)                                        \
  __builtin_amdgcn_global_load_lds(                            \
      (const __attribute__((address_space(1))) void*)(gp),     \
      (__attribute__((address_space(3))) void*)(lp), 16, 0, 0)

// ---------------- q_c fp32 (strided) -> Abf bf16 [32768][1536] ----------------
__global__ __launch_bounds__(256) void aconv_kernel(const float* __restrict__ qkv,
                                                    ushort_t* __restrict__ Abf) {
  int g = blockIdx.x * 256 + threadIdx.x;   // one 8-elem group per thread
  int row = g / 192;                        // 192 groups per row
  int col = (g - row * 192) * 8;
  const float* s = qkv + (size_t)row * ROWW + col;
  f32x4 a = *(const f32x4*)s;
  f32x4 b = *(const f32x4*)(s + 4);
  short8 v;
  v[0] = f2bf(a[0]); v[1] = f2bf(a[1]); v[2] = f2bf(a[2]); v[3] = f2bf(a[3]);
  v[4] = f2bf(b[0]); v[5] = f2bf(b[1]); v[6] = f2bf(b[2]); v[7] = f2bf(b[3]);
  *(short8*)(Abf + (size_t)row * QL + col) = v;
}

// ---------------- Wq transpose + fp32->bf16: Wq[1536][3072] -> Wt[3072][1536] ----
__global__ void wq_t_kernel(const float* __restrict__ Wq, ushort_t* __restrict__ Wt) {
  __shared__ float tile[32][33];
  int tx = threadIdx.x, ty = threadIdx.y;   // (32, 8)
  int n0 = blockIdx.x * 32, k0 = blockIdx.y * 32;
#pragma unroll
  for (int j = 0; j < 32; j += 8)
    tile[ty + j][tx] = Wq[(size_t)(k0 + ty + j) * NQ + n0 + tx];
  __syncthreads();
#pragma unroll
  for (int j = 0; j < 32; j += 8)
    Wt[(size_t)(n0 + ty + j) * QL + k0 + tx] = f2bf(tile[tx][ty + j]);
}

// ---------------- bf16 GEMM (Abf @ Wt^T), 256^2 fine-4-phase + RoPE epilogue ----
// LDS: [par][A/B][khalf][256 rows x 32 elems]; each K-half contiguous 16KB.
// Swizzle: 16B chunk c of row r holds global chunk c ^ ((r>>1)&3) (2-way = free).
// Schedule per tile t (par=t&1):
//   ph0 (hf0,ks0): 8 ds_read; stage A-K1(t+1);              bar; lgkm; 16 MFMA; bar
//   ph1 (hf1,ks0): 4 ds_read; vmcnt(6); stage B-K1(t+1);    bar; lgkm; 16 MFMA; bar
//   ph2 (hf0,ks1): 8 ds_read; stage A-K0(t+2);              bar; lgkm; 16 MFMA; bar
//   ph3 (hf1,ks1): 4 ds_read; vmcnt(6); stage B-K0(t+2);    bar; lgkm; 16 MFMA; bar
// vmcnt audit (2 gloads/stage): ph1's vmcnt covers ph2-3 reads (K1(t), staged
// t-1 ph0/ph1; 3 newer stages = 6 loads). ph3's covers next tile's ph0-1 reads
// (K0(t+1), staged t ph2 / t-1 ph3... B-K0(t+1) @ t-1 ph3; newer: t ph0,1,2 = 6).
// Tail: ph1 N=0 at t=KT-1; ph3 N=4 at t=KT-2, skip at KT-1.
__global__ __launch_bounds__(512, 2) void gemm_rope_kernel(
    const ushort_t* __restrict__ Abf, const int* __restrict__ pos,
    const ushort_t* __restrict__ wt, float* __restrict__ out_q) {
  __shared__ ushort_t lds[2][2][2][256 * 32];   // 128 KiB

  int bid = blockIdx.x;
  // XCD swizzle (1536 % 8 == 0 -> bijective): 192 consecutive vb per XCD
  int vb = (bid & 7) * (MT * NT / 8) + (bid >> 3);
  int m0 = (vb / NT) * BM;
  int n0 = (vb % NT) * BN;

  int tid = threadIdx.x;
  int wv = tid >> 6, ln = tid & 63;
  int l16 = ln & 15, lq4 = ln >> 4;
  int wm = wv >> 2, wn = wv & 3;          // 2x4 wave grid; wave owns 128x64 of C

  // ---- staging: wave wv covers rows [wv*32, wv*32+32) of the 256-row half ----
  // instr lane map: row = ln>>2 (16 rows/instr), chunk = ln&3; inverse-swizzle
  // source chunk by key ((row)>>1)&3 = (ln>>3)&3.
  int srow = wv * 32 + (ln >> 2);
  int schunk = ((ln & 3) ^ ((ln >> 3) & 3)) * 8;
  const ushort_t* aS = Abf + (size_t)(m0 + srow) * QL + schunk;
  const ushort_t* bS = wt  + (size_t)(n0 + srow) * QL + schunk;
  int sdst = wv * 32 * 32;                // elems; +512 for second instr (16 rows)

#define STG(PAR, AB, KH, TT, SRC) do {                                         \
    GLOAD16((SRC) + (size_t)(TT) * BK + (KH) * 32,           &lds[PAR][AB][KH][sdst]);       \
    GLOAD16((SRC) + (size_t)(TT) * BK + (KH) * 32 + 16 * QL, &lds[PAR][AB][KH][sdst + 512]); \
  } while (0)

  // ---- fragment read addressing (swizzled): key = (row>>1)&3 = (l16>>1)&3 ----
  int rkey = (l16 >> 1) & 3;
  int aoff = (wm * 128 + l16) * 32 + (lq4 ^ rkey) * 8;   // + mi*512
  int boff = (wn * 64  + l16) * 32 + (lq4 ^ rkey) * 8;   // + ni*512

  f32x4 acc[8][4];
#pragma unroll
  for (int i = 0; i < 8; ++i)
#pragma unroll
    for (int j = 0; j < 4; ++j) acc[i][j] = (f32x4)0.0f;

  // ---- prologue: 6 half-tiles (12 loads/wave) ----
  STG(0, 0, 0, 0, aS);   // A-K0(0)
  STG(0, 1, 0, 0, bS);   // B-K0(0)
  STG(0, 0, 1, 0, aS);   // A-K1(0)
  STG(0, 1, 1, 0, bS);   // B-K1(0)
  STG(1, 0, 0, 1, aS);   // A-K0(1)
  STG(1, 1, 0, 1, bS);   // B-K0(1)
  asm volatile("s_waitcnt vmcnt(8)" ::: "memory");   // K0(0) halves landed
  __builtin_amdgcn_s_barrier();

#define MFMA_PHASE(ACCBASE)                                                    \
  __builtin_amdgcn_s_barrier();                                                \
  asm volatile("s_waitcnt lgkmcnt(0)" ::: "memory");                           \
  __builtin_amdgcn_sched_barrier(0);                                           \
  __builtin_amdgcn_s_setprio(1);                                               \
  _Pragma("unroll")                                                            \
  for (int q = 0; q < 4; ++q)                                                  \
    _Pragma("unroll")                                                          \
    for (int n = 0; n < 4; ++n)                                                \
      acc[(ACCBASE) + q][n] = __builtin_amdgcn_mfma_f32_16x16x32_bf16(         \
          af[q], bf[n], acc[(ACCBASE) + q][n], 0, 0, 0);                       \
  __builtin_amdgcn_s_setprio(0);                                               \
  __builtin_amdgcn_s_barrier();

  for (int t = 0; t < KT; ++t) {
    int par = t & 1;
    const ushort_t* Ak0 = &lds[par][0][0][0];
    const ushort_t* Bk0 = &lds[par][1][0][0];
    const ushort_t* Ak1 = &lds[par][0][1][0];
    const ushort_t* Bk1 = &lds[par][1][1][0];
    short8 af[4], bf[4];

    // ---- phase 0: (hf0, ks0) ----
#pragma unroll
    for (int q = 0; q < 4; ++q) af[q] = *(const short8*)(Ak0 + aoff + q * 512);
#pragma unroll
    for (int n = 0; n < 4; ++n) bf[n] = *(const short8*)(Bk0 + boff + n * 512);
    if (t + 1 < KT) STG(par ^ 1, 0, 1, t + 1, aS);   // A-K1(t+1)
    MFMA_PHASE(0)

    // ---- phase 1: (hf1, ks0), B regs reused ----
#pragma unroll
    for (int q = 0; q < 4; ++q) af[q] = *(const short8*)(Ak0 + aoff + (4 + q) * 512);
    if (t < KT - 1) { asm volatile("s_waitcnt vmcnt(6)" ::: "memory"); }
    else            { asm volatile("s_waitcnt vmcnt(0)" ::: "memory"); }
    if (t + 1 < KT) STG(par ^ 1, 1, 1, t + 1, bS);   // B-K1(t+1)
    MFMA_PHASE(4)

    // ---- phase 2: (hf0, ks1) ----
#pragma unroll
    for (int q = 0; q < 4; ++q) af[q] = *(const short8*)(Ak1 + aoff + q * 512);
#pragma unroll
    for (int n = 0; n < 4; ++n) bf[n] = *(const short8*)(Bk1 + boff + n * 512);
    if (t + 2 < KT) STG(par, 0, 0, t + 2, aS);       // A-K0(t+2)
    MFMA_PHASE(0)

    // ---- phase 3: (hf1, ks1), B regs reused ----
#pragma unroll
    for (int q = 0; q < 4; ++q) af[q] = *(const short8*)(Ak1 + aoff + (4 + q) * 512);
    if (t < KT - 2)       { asm volatile("s_waitcnt vmcnt(6)" ::: "memory"); }
    else if (t == KT - 2) { asm volatile("s_waitcnt vmcnt(4)" ::: "memory"); }
    if (t + 2 < KT) STG(par, 1, 0, t + 2, bS);       // B-K0(t+2)
    MFMA_PHASE(4)
  }

  // ---- epilogue: C/D layout col = lane&15, row = (lane>>4)*4 + reg ----
  int gn = n0 + wn * 64;
  bool ropew = ((gn % 192) == 128);        // rope region is 64-wide, 64-aligned
  if (!ropew) {
#pragma unroll
    for (int mi = 0; mi < 8; ++mi)
#pragma unroll
      for (int r = 0; r < 4; ++r) {
        int t = m0 + wm * 128 + mi * 16 + lq4 * 4 + r;
        float* rowp = out_q + (size_t)t * NQ + gn + l16;
        rowp[0]  = acc[mi][0][r];
        rowp[16] = acc[mi][1][r];
        rowp[32] = acc[mi][2][r];
        rowp[48] = acc[mi][3][r];
      }
  } else {
    float invf0 = __expf((float)l16 * NLOG);
    float invf1 = __expf((float)(l16 + 16) * NLOG);
#pragma unroll
    for (int mi = 0; mi < 8; ++mi)
#pragma unroll
      for (int r = 0; r < 4; ++r) {
        int t = m0 + wm * 128 + mi * 16 + lq4 * 4 + r;
        float p = (float)pos[t];
        float s0, c0, s1, c1;
        __sincosf(p * invf0, &s0, &c0);
        __sincosf(p * invf1, &s1, &c1);
        float x1a = acc[mi][0][r], x1b = acc[mi][1][r];
        float x2a = acc[mi][2][r], x2b = acc[mi][3][r];
        float* rowp = out_q + (size_t)t * NQ + gn + l16;
        rowp[0]  = x1a * c0 - x2a * s0;
        rowp[16] = x1b * c1 - x2b * s1;
        rowp[32] = x2a * c0 + x1a * s0;
        rowp[48] = x2b * c1 + x1b * s1;
      }
  }
}

// ---------------- kv_c copy + k_pe RoPE + kv_cache scatter ----------------
__global__ void kv_kernel(const float* __restrict__ qkv, const int* __restrict__ pos,
                          const int* __restrict__ slots,
                          float* __restrict__ out_kvc, float* __restrict__ out_kpe,
                          float* __restrict__ out_cache) {
  int tok = blockIdx.x * 4 + (threadIdx.x >> 6);
  int lane = threadIdx.x & 63;
  const float* src = qkv + (size_t)tok * ROWW + QL;   // kv_c (512) then k_pe (64)
  float* dkv = out_kvc + (size_t)tok * KVL;
  int slot = slots[tok];
  float* dc = out_cache + (size_t)slot * HS;
#pragma unroll
  for (int i = 0; i < 2; ++i) {
    f32x4 v = *(const f32x4*)(src + (size_t)(lane + 64 * i) * 4);
    *(f32x4*)(dkv + (size_t)(lane + 64 * i) * 4) = v;
    *(f32x4*)(dc + (size_t)(lane + 64 * i) * 4) = v;
  }
  if (lane < 32) {
    float x1 = src[KVL + lane], x2 = src[KVL + 32 + lane];
    float p = (float)pos[tok];
    float invf = __expf((float)lane * NLOG);
    float s, c;
    __sincosf(p * invf, &s, &c);
    float r1 = x1 * c - x2 * s;
    float r2 = x2 * c + x1 * s;
    out_kpe[(size_t)tok * RD + lane] = r1;
    out_kpe[(size_t)tok * RD + 32 + lane] = r2;
    dc[KVL + lane] = r1;
    dc[KVL + 32 + lane] = r2;
  }
}

extern "C" void kernel_launch(void* const* d_in, const int* in_sizes, int n_in,
                              void* d_out, int out_size, void* d_ws, size_t ws_size,
                              hipStream_t stream) {
  const float* qkv       = (const float*)d_in[0];
  const int*   positions = (const int*)d_in[1];
  const float* Wq        = (const float*)d_in[2];
  // d_in[3] = kv_cache input (fully overwritten: slot_mapping is a permutation)
  const int*   slots     = (const int*)d_in[4];

  float* out_q     = (float*)d_out;
  float* out_kvc   = out_q   + (size_t)T_TOK * NQ;
  float* out_kpe   = out_kvc + (size_t)T_TOK * KVL;
  float* out_cache = out_kpe + (size_t)T_TOK * RD;

  // scratch: Abf bf16 (100.7 MB) + Wt bf16 (9.4 MB).
  // Prefer d_ws; else alias into out_kvc.. region (147.5 MB contiguous),
  // which kv_kernel fully rewrites afterwards (stream-ordered, deterministic).
  size_t abf_bytes = (size_t)T_TOK * QL * sizeof(ushort_t);   // 100,663,296
  size_t wt_bytes  = (size_t)NQ * QL * sizeof(ushort_t);      //   9,437,184
  char* scratch = (ws_size >= abf_bytes + wt_bytes) ? (char*)d_ws : (char*)out_kvc;
  ushort_t* Abf = (ushort_t*)scratch;
  ushort_t* Wt  = (ushort_t*)(scratch + abf_bytes);

  aconv_kernel<<<dim3(T_TOK * 192 / 256), dim3(256), 0, stream>>>(qkv, Abf);
  wq_t_kernel<<<dim3(NQ / 32, QL / 32), dim3(32, 8), 0, stream>>>(Wq, Wt);
  gemm_rope_kernel<<<dim3(MT * NT), dim3(512), 0, stream>>>(Abf, positions, Wt, out_q);
  kv_kernel<<<dim3(T_TOK / 4), dim3(256), 0, stream>>>(qkv, positions, slots,
                                                       out_kvc, out_kpe, out_cache);
}

// Round 5
// 439.259 us; speedup vs baseline: 1.8880x; 1.0026x over previous
//
#include <hip/hip_runtime.h>
#include <hip/hip_bf16.h>
#include <stdint.h>

typedef unsigned short ushort_t;
typedef __attribute__((ext_vector_type(4))) float f32x4;
typedef __attribute__((ext_vector_type(8))) short short8;

#define T_TOK 32768
#define QL    1536
#define KVL   512
#define RD    64
#define NQ    3072     // 16 heads * 192
#define ROWW  2112     // qkv_lora row: 1536+512+64
#define HS    576      // 512+64

// 256^2 overlap-scheduled GEMM geometry
#define BM 256
#define BN 256
#define BK 64
#define KT (QL / BK)       // 24 K-tiles
#define MT (T_TOK / BM)    // 128
#define NT (NQ / BN)       // 12

// -ln(10000)/32 : inv_freq_i = exp(i * NLOG) = 10000^(-i/32)
#define NLOG (-0.28782313662425572f)

static __device__ __forceinline__ short f2bf(float x) {
  __hip_bfloat16 h = __float2bfloat16(x);
  return *reinterpret_cast<short*>(&h);
}

// async global->LDS, 16B per lane; LDS dest = wave-uniform base + lane*16
#define GLOAD16(gp, lp)                                        \
  __builtin_amdgcn_global_load_lds(                            \
      (const __attribute__((address_space(1))) void*)(gp),     \
      (__attribute__((address_space(3))) void*)(lp), 16, 0, 0)

// ---------------- q_c fp32 (strided) -> Abf bf16 [32768][1536] ----------------
__global__ __launch_bounds__(256) void aconv_kernel(const float* __restrict__ qkv,
                                                    ushort_t* __restrict__ Abf) {
  int g = blockIdx.x * 256 + threadIdx.x;   // one 8-elem group per thread
  int row = g / 192;                        // 192 groups per row
  int col = (g - row * 192) * 8;
  const float* s = qkv + (size_t)row * ROWW + col;
  f32x4 a = *(const f32x4*)s;
  f32x4 b = *(const f32x4*)(s + 4);
  short8 v;
  v[0] = f2bf(a[0]); v[1] = f2bf(a[1]); v[2] = f2bf(a[2]); v[3] = f2bf(a[3]);
  v[4] = f2bf(b[0]); v[5] = f2bf(b[1]); v[6] = f2bf(b[2]); v[7] = f2bf(b[3]);
  *(short8*)(Abf + (size_t)row * QL + col) = v;
}

// ---------------- Wq transpose + fp32->bf16: Wq[1536][3072] -> Wt[3072][1536] ----
__global__ void wq_t_kernel(const float* __restrict__ Wq, ushort_t* __restrict__ Wt) {
  __shared__ float tile[32][33];
  int tx = threadIdx.x, ty = threadIdx.y;   // (32, 8)
  int n0 = blockIdx.x * 32, k0 = blockIdx.y * 32;
#pragma unroll
  for (int j = 0; j < 32; j += 8)
    tile[ty + j][tx] = Wq[(size_t)(k0 + ty + j) * NQ + n0 + tx];
  __syncthreads();
#pragma unroll
  for (int j = 0; j < 32; j += 8)
    Wt[(size_t)(n0 + ty + j) * QL + k0 + tx] = f2bf(tile[tx][ty + j]);
}

// ---------------- bf16 GEMM (Abf @ Wt^T), 256^2 overlap schedule + RoPE --------
// LDS: [par][A/B][khalf][256 x 32]; swizzle: chunk c of row r holds global
// chunk c ^ ((r>>1)&3)  (2-way bank alias = free).
// Per tile t (par=t&1), 2 barriers, 1 vmcnt, compiler-managed lgkm waits:
//   [schedbar; vmcnt(4); s_barrier; schedbar]
//   r0: af(K0,hf0)x4 + bf(K0)x4;  r1: af(K0,hf1)x4
//   S1,S2: stage A/B-K1(t+1) -> lds[par^1][*][1]   (last read t-1 2nd half)
//   c0 (acc0-3, waits r0 via data dep, r1 drains under it); c1 (acc4-7)
//   r2: af(K1,hf0)x4 + bf(K1)x4;  r3: af(K1,hf1)x4  (K1(t) valid since boundary)
//   [schedbar; s_barrier; schedbar]   // K0(t) reads retired block-wide
//   S3,S4: stage A/B-K0(t+2) -> lds[par][*][0]
//   c2 (acc0-3); c3 (acc4-7)
// vmcnt audit: at boundary of tile t, outstanding = K0(t)[t-2], K1(t)[t-1],
// K0(t+1)[t-1] = 12 -> vmcnt(4) keeps newest 4. Tail: t=KT-1 -> vmcnt(0).
__global__ __launch_bounds__(512, 2) void gemm_rope_kernel(
    const ushort_t* __restrict__ Abf, const int* __restrict__ pos,
    const ushort_t* __restrict__ wt, float* __restrict__ out_q) {
  __shared__ ushort_t lds[2][2][2][256 * 32];   // 128 KiB

  int bid = blockIdx.x;
  // XCD swizzle (1536 % 8 == 0 -> bijective): 192 consecutive vb per XCD
  int vb = (bid & 7) * (MT * NT / 8) + (bid >> 3);
  int m0 = (vb / NT) * BM;
  int n0 = (vb % NT) * BN;

  int tid = threadIdx.x;
  int wv = tid >> 6, ln = tid & 63;
  int l16 = ln & 15, lq4 = ln >> 4;
  int wm = wv >> 2, wn = wv & 3;          // 2x4 wave grid; wave owns 128x64 of C

  // ---- staging: wave wv covers rows [wv*32, wv*32+32); row = ln>>2, chunk=ln&3
  // inverse-swizzle source chunk by key (row>>1)&3 = (ln>>3)&3.
  int srow = wv * 32 + (ln >> 2);
  int schunk = ((ln & 3) ^ ((ln >> 3) & 3)) * 8;
  const ushort_t* aS = Abf + (size_t)(m0 + srow) * QL + schunk;
  const ushort_t* bS = wt  + (size_t)(n0 + srow) * QL + schunk;
  int sdst = wv * 32 * 32;                // elems; +512 for second instr

#define STG(PAR, AB, KH, TT, SRC) do {                                         \
    GLOAD16((SRC) + (size_t)(TT) * BK + (KH) * 32,           &lds[PAR][AB][KH][sdst]);       \
    GLOAD16((SRC) + (size_t)(TT) * BK + (KH) * 32 + 16 * QL, &lds[PAR][AB][KH][sdst + 512]); \
  } while (0)

  // ---- fragment read addressing (swizzled): key = (l16>>1)&3 ----
  int rkey = (l16 >> 1) & 3;
  int aoff = (wm * 128 + l16) * 32 + (lq4 ^ rkey) * 8;   // + mi*512
  int boff = (wn * 64  + l16) * 32 + (lq4 ^ rkey) * 8;   // + ni*512

  f32x4 acc[8][4];
#pragma unroll
  for (int i = 0; i < 8; ++i)
#pragma unroll
    for (int j = 0; j < 4; ++j) acc[i][j] = (f32x4)0.0f;

  // ---- prologue: K0(0), K1(0), K0(1) = 12 loads ----
  STG(0, 0, 0, 0, aS);   // A-K0(0)
  STG(0, 1, 0, 0, bS);   // B-K0(0)
  STG(0, 0, 1, 0, aS);   // A-K1(0)
  STG(0, 1, 1, 0, bS);   // B-K1(0)
  STG(1, 0, 0, 1, aS);   // A-K0(1)
  STG(1, 1, 0, 1, bS);   // B-K0(1)

#define CLUSTER(ACCBASE, AF)                                                   \
  __builtin_amdgcn_s_setprio(1);                                               \
  _Pragma("unroll")                                                            \
  for (int q = 0; q < 4; ++q)                                                  \
    _Pragma("unroll")                                                          \
    for (int n = 0; n < 4; ++n)                                                \
      acc[(ACCBASE) + q][n] = __builtin_amdgcn_mfma_f32_16x16x32_bf16(         \
          AF[q], bf[n], acc[(ACCBASE) + q][n], 0, 0, 0);                       \
  __builtin_amdgcn_s_setprio(0);

#pragma unroll 2
  for (int t = 0; t < KT; ++t) {
    int par = t & 1;
    const ushort_t* Ak0 = &lds[par][0][0][0];
    const ushort_t* Bk0 = &lds[par][1][0][0];
    const ushort_t* Ak1 = &lds[par][0][1][0];
    const ushort_t* Bk1 = &lds[par][1][1][0];
    short8 af0[4], af1[4], bf[4];

    // ---- tile boundary ----
    __builtin_amdgcn_sched_barrier(0);
    if (t == KT - 1) { asm volatile("s_waitcnt vmcnt(0)" ::: "memory"); }
    else             { asm volatile("s_waitcnt vmcnt(4)" ::: "memory"); }
    __builtin_amdgcn_s_barrier();
    __builtin_amdgcn_sched_barrier(0);

    // r0 + r1 (K0 of tile t)
#pragma unroll
    for (int q = 0; q < 4; ++q) af0[q] = *(const short8*)(Ak0 + aoff + q * 512);
#pragma unroll
    for (int n = 0; n < 4; ++n) bf[n]  = *(const short8*)(Bk0 + boff + n * 512);
#pragma unroll
    for (int q = 0; q < 4; ++q) af1[q] = *(const short8*)(Ak0 + aoff + (4 + q) * 512);
    // S1,S2: K1(t+1)
    if (t + 1 < KT) { STG(par ^ 1, 0, 1, t + 1, aS); STG(par ^ 1, 1, 1, t + 1, bS); }

    CLUSTER(0, af0)     // c0: compiler waits r0 regs; r1 drains underneath
    CLUSTER(4, af1)     // c1

    // r2 + r3 (K1 of tile t) — valid since boundary; drain under c1/barrier
    short8 ag0[4], ag1[4], bg[4];
#pragma unroll
    for (int q = 0; q < 4; ++q) ag0[q] = *(const short8*)(Ak1 + aoff + q * 512);
#pragma unroll
    for (int n = 0; n < 4; ++n) bg[n]  = *(const short8*)(Bk1 + boff + n * 512);
#pragma unroll
    for (int q = 0; q < 4; ++q) ag1[q] = *(const short8*)(Ak1 + aoff + (4 + q) * 512);

    // ---- mid barrier: K0(t) reads retired block-wide (pinned above) ----
    __builtin_amdgcn_sched_barrier(0);
    __builtin_amdgcn_s_barrier();
    __builtin_amdgcn_sched_barrier(0);

    // S3,S4: K0(t+2) into the region r0/r1 just vacated
    if (t + 2 < KT) { STG(par, 0, 0, t + 2, aS); STG(par, 1, 0, t + 2, bS); }

    {
      short8* bfp = bg;   // alias for macro
#define bf bg
      CLUSTER(0, ag0)   // c2
      CLUSTER(4, ag1)   // c3
#undef bf
      (void)bfp;
    }
  }

  // ---- epilogue: C/D layout col = lane&15, row = (lane>>4)*4 + reg ----
  int gn = n0 + wn * 64;
  bool ropew = ((gn % 192) == 128);        // rope region is 64-wide, 64-aligned
  if (!ropew) {
#pragma unroll
    for (int mi = 0; mi < 8; ++mi)
#pragma unroll
      for (int r = 0; r < 4; ++r) {
        int t = m0 + wm * 128 + mi * 16 + lq4 * 4 + r;
        float* rowp = out_q + (size_t)t * NQ + gn + l16;
        rowp[0]  = acc[mi][0][r];
        rowp[16] = acc[mi][1][r];
        rowp[32] = acc[mi][2][r];
        rowp[48] = acc[mi][3][r];
      }
  } else {
    float invf0 = __expf((float)l16 * NLOG);
    float invf1 = __expf((float)(l16 + 16) * NLOG);
#pragma unroll
    for (int mi = 0; mi < 8; ++mi)
#pragma unroll
      for (int r = 0; r < 4; ++r) {
        int t = m0 + wm * 128 + mi * 16 + lq4 * 4 + r;
        float p = (float)pos[t];
        float s0, c0, s1, c1;
        __sincosf(p * invf0, &s0, &c0);
        __sincosf(p * invf1, &s1, &c1);
        float x1a = acc[mi][0][r], x1b = acc[mi][1][r];
        float x2a = acc[mi][2][r], x2b = acc[mi][3][r];
        float* rowp = out_q + (size_t)t * NQ + gn + l16;
        rowp[0]  = x1a * c0 - x2a * s0;
        rowp[16] = x1b * c1 - x2b * s1;
        rowp[32] = x2a * c0 + x1a * s0;
        rowp[48] = x2b * c1 + x1b * s1;
      }
  }
}

// ---------------- kv_c copy + k_pe RoPE + kv_cache scatter ----------------
__global__ void kv_kernel(const float* __restrict__ qkv, const int* __restrict__ pos,
                          const int* __restrict__ slots,
                          float* __restrict__ out_kvc, float* __restrict__ out_kpe,
                          float* __restrict__ out_cache) {
  int tok = blockIdx.x * 4 + (threadIdx.x >> 6);
  int lane = threadIdx.x & 63;
  const float* src = qkv + (size_t)tok * ROWW + QL;   // kv_c (512) then k_pe (64)
  float* dkv = out_kvc + (size_t)tok * KVL;
  int slot = slots[tok];
  float* dc = out_cache + (size_t)slot * HS;
#pragma unroll
  for (int i = 0; i < 2; ++i) {
    f32x4 v = *(const f32x4*)(src + (size_t)(lane + 64 * i) * 4);
    *(f32x4*)(dkv + (size_t)(lane + 64 * i) * 4) = v;
    *(f32x4*)(dc + (size_t)(lane + 64 * i) * 4) = v;
  }
  if (lane < 32) {
    float x1 = src[KVL + lane], x2 = src[KVL + 32 + lane];
    float p = (float)pos[tok];
    float invf = __expf((float)lane * NLOG);
    float s, c;
    __sincosf(p * invf, &s, &c);
    float r1 = x1 * c - x2 * s;
    float r2 = x2 * c + x1 * s;
    out_kpe[(size_t)tok * RD + lane] = r1;
    out_kpe[(size_t)tok * RD + 32 + lane] = r2;
    dc[KVL + lane] = r1;
    dc[KVL + 32 + lane] = r2;
  }
}

extern "C" void kernel_launch(void* const* d_in, const int* in_sizes, int n_in,
                              void* d_out, int out_size, void* d_ws, size_t ws_size,
                              hipStream_t stream) {
  const float* qkv       = (const float*)d_in[0];
  const int*   positions = (const int*)d_in[1];
  const float* Wq        = (const float*)d_in[2];
  // d_in[3] = kv_cache input (fully overwritten: slot_mapping is a permutation)
  const int*   slots     = (const int*)d_in[4];

  float* out_q     = (float*)d_out;
  float* out_kvc   = out_q   + (size_t)T_TOK * NQ;
  float* out_kpe   = out_kvc + (size_t)T_TOK * KVL;
  float* out_cache = out_kpe + (size_t)T_TOK * RD;

  // scratch: Abf bf16 (100.7 MB) + Wt bf16 (9.4 MB).
  // Prefer d_ws; else alias into out_kvc.. region (147.5 MB contiguous),
  // which kv_kernel fully rewrites afterwards (stream-ordered, deterministic).
  size_t abf_bytes = (size_t)T_TOK * QL * sizeof(ushort_t);   // 100,663,296
  size_t wt_bytes  = (size_t)NQ * QL * sizeof(ushort_t);      //   9,437,184
  char* scratch = (ws_size >= abf_bytes + wt_bytes) ? (char*)d_ws : (char*)out_kvc;
  ushort_t* Abf = (ushort_t*)scratch;
  ushort_t* Wt  = (ushort_t*)(scratch + abf_bytes);

  aconv_kernel<<<dim3(T_TOK * 192 / 256), dim3(256), 0, stream>>>(qkv, Abf);
  wq_t_kernel<<<dim3(NQ / 32, QL / 32), dim3(32, 8), 0, stream>>>(Wq, Wt);
  gemm_rope_kernel<<<dim3(MT * NT), dim3(512), 0, stream>>>(Abf, positions, Wt, out_q);
  kv_kernel<<<dim3(T_TOK / 4), dim3(256), 0, stream>>>(qkv, positions, slots,
                                                       out_kvc, out_kpe, out_cache);
}